// Round 1
// baseline (38.734 us; speedup 1.0000x reference)
//
#include <hip/hip_runtime.h>

#define NROWS 8192
#define DIN   128
#define DOUT  64

// K1: f = feat @ W^T + b  (one wave per row, lane = output col d)
//     u_j = f[j,:] . aw[0:64]  via wave shuffle reduce
__global__ __launch_bounds__(256) void k_f_u(
    const float* __restrict__ feat, const float* __restrict__ W,
    const float* __restrict__ b, const float* __restrict__ aw,
    float* __restrict__ f, float* __restrict__ u)
{
    __shared__ float Wl[DOUT * (DIN + 1)];  // pad 128->129: bank = (lane + k) % 32, 2-way = free
    const int tid = threadIdx.x;
    for (int i = tid; i < DOUT * DIN; i += 256) {
        int d = i >> 7, k = i & 127;
        Wl[d * (DIN + 1) + k] = W[i];
    }
    __syncthreads();

    const int lane = tid & 63;
    const int wave = tid >> 6;
    const int row  = blockIdx.x * 4 + wave;

    const float* fr   = feat + (size_t)row * DIN;
    const float* wrow = &Wl[lane * (DIN + 1)];
    float acc = 0.f;
    #pragma unroll
    for (int k = 0; k < DIN; k += 4) {
        float4 fv = *reinterpret_cast<const float4*>(fr + k);  // same addr all lanes: broadcast
        acc = fmaf(fv.x, wrow[k],     acc);
        acc = fmaf(fv.y, wrow[k + 1], acc);
        acc = fmaf(fv.z, wrow[k + 2], acc);
        acc = fmaf(fv.w, wrow[k + 3], acc);
    }
    acc += b[lane];
    f[(size_t)row * DOUT + lane] = acc;

    float t = acc * aw[lane];
    #pragma unroll
    for (int off = 32; off; off >>= 1) t += __shfl_down(t, off);
    if (lane == 0) u[row] = t;
}

// K2: p = softmax(-u): m = min(u); e_j = exp(m - u_j); invS = 1/sum(e)
__global__ __launch_bounds__(1024) void k_softmax(
    const float* __restrict__ u, float* __restrict__ e, float* __restrict__ invS)
{
    __shared__ float red[16];
    const int tid = threadIdx.x;
    const int lane = tid & 63, wave = tid >> 6;

    float vals[8];
    float mn = 3.4e38f;
    #pragma unroll
    for (int i = 0; i < 8; ++i) {
        vals[i] = u[tid + i * 1024];
        mn = fminf(mn, vals[i]);
    }
    #pragma unroll
    for (int off = 32; off; off >>= 1) mn = fminf(mn, __shfl_down(mn, off));
    if (lane == 0) red[wave] = mn;
    __syncthreads();
    if (tid == 0) {
        float m = red[0];
        #pragma unroll
        for (int w = 1; w < 16; ++w) m = fminf(m, red[w]);
        red[0] = m;
    }
    __syncthreads();
    const float m = red[0];
    __syncthreads();  // red reused below

    float s = 0.f;
    #pragma unroll
    for (int i = 0; i < 8; ++i) {
        float ev = expf(m - vals[i]);   // arg <= 0, no overflow
        e[tid + i * 1024] = ev;
        s += ev;
    }
    #pragma unroll
    for (int off = 32; off; off >>= 1) s += __shfl_down(s, off);
    if (lane == 0) red[wave] = s;
    __syncthreads();
    if (tid == 0) {
        float S = 0.f;
        #pragma unroll
        for (int w = 0; w < 16; ++w) S += red[w];
        *invS = 1.0f / S;
    }
}

// K3: r[d] = invS * sum_j e[j] * f[j,d]   (one block per d)
__global__ __launch_bounds__(256) void k_colsum(
    const float* __restrict__ f, const float* __restrict__ e,
    const float* __restrict__ invS, float* __restrict__ r)
{
    __shared__ float red[256];
    const int d = blockIdx.x;
    const int tid = threadIdx.x;
    float acc = 0.f;
    for (int j = tid; j < NROWS; j += 256)
        acc = fmaf(e[j], f[(size_t)j * DOUT + d], acc);
    red[tid] = acc;
    __syncthreads();
    #pragma unroll
    for (int s = 128; s; s >>= 1) {
        if (tid < s) red[tid] += red[tid + s];
        __syncthreads();
    }
    if (tid == 0) r[d] = red[0] * (*invS);
}

// K4: out[i,:] = r  for all 8192 rows (float4 stores, overwrites f in d_out)
__global__ __launch_bounds__(256) void k_bcast(
    const float* __restrict__ r, float4* __restrict__ out)
{
    __shared__ float4 rl[16];
    if (threadIdx.x < 16) rl[threadIdx.x] = reinterpret_cast<const float4*>(r)[threadIdx.x];
    __syncthreads();
    const int i = blockIdx.x * 256 + threadIdx.x;  // 512*256 = 131072 = NROWS*DOUT/4
    out[i] = rl[i & 15];
}

extern "C" void kernel_launch(void* const* d_in, const int* in_sizes, int n_in,
                              void* d_out, int out_size, void* d_ws, size_t ws_size,
                              hipStream_t stream) {
    const float* feat = (const float*)d_in[0];
    // d_in[1]: edgelist int64 -- structurally max+1 == 8192 == NROWS, unused
    const float* W  = (const float*)d_in[2];
    const float* b  = (const float*)d_in[3];
    const float* aw = (const float*)d_in[4];
    // d_in[5]: a_b -- cancels in the row softmax, unused

    float* f    = (float*)d_out;            // [NROWS*DOUT] staged in output buffer
    float* u    = (float*)d_ws;             // 8192
    float* e    = u + NROWS;                // 8192
    float* r    = e + NROWS;                // 64   (16B-aligned: 2*8192 floats before it)
    float* invS = r + DOUT;                 // 1

    k_f_u    <<<NROWS / 4, 256, 0, stream>>>(feat, W, b, aw, f, u);
    k_softmax<<<1, 1024, 0, stream>>>(u, e, invS);
    k_colsum <<<DOUT, 256, 0, stream>>>(f, e, invS, r);
    k_bcast  <<<NROWS * DOUT / 4 / 256, 256, 0, stream>>>(r, (float4*)d_out);
}